// Round 6
// baseline (639.871 us; speedup 1.0000x reference)
//
#include <hip/hip_runtime.h>
#include <hip/hip_bf16.h>

// Problem constants (from reference)
#define B_   2
#define T_   2048
#define D_   2048
#define H_   16
#define KV_  4
#define HD_  128
#define BT_  (B_*T_)         // 4096 token rows
#define QKVP 3072            // per-token pitch of merged [q|k|v] buffer
#define KOFF 2048            // k segment offset within a token row
#define VOFF 2560            // v segment offset within a token row
static constexpr float EPS_ = 1e-6f;

typedef unsigned short u16;
typedef __attribute__((ext_vector_type(8))) short short8;          // 8 bf16 = 16 B
typedef __attribute__((ext_vector_type(4))) float f32x4;           // MFMA acc
typedef __attribute__((ext_vector_type(4))) unsigned short u16x4;  // 8 B

__device__ __forceinline__ u16 f2bf(float f){
    unsigned u = __float_as_uint(f);
    u += 0x7FFF + ((u >> 16) & 1);          // round-to-nearest-even
    return (u16)(u >> 16);
}
__device__ __forceinline__ float bf2f(u16 u){
    return __uint_as_float((unsigned)u << 16);
}

// Async global->LDS, 16 B per lane. LDS dest must be wave-uniform base + lane*16.
__device__ __forceinline__ void async_copy16(const void* g, void* l) {
    __builtin_amdgcn_global_load_lds(
        (const __attribute__((address_space(1))) unsigned int*)g,
        (__attribute__((address_space(3))) unsigned int*)l, 16, 0, 0);
}

// ---------------------------------------------------------------------------
// f32 -> bf16 elementwise convert (n % 4 == 0)
// ---------------------------------------------------------------------------
__global__ __launch_bounds__(256) void cvt_f32_bf16_kernel(
    const float* __restrict__ in, u16* __restrict__ out, int n)
{
    const int i = (blockIdx.x*256 + threadIdx.x)*4;
    if (i < n) {
        float4 v = *(const float4*)&in[i];
        u16x4 w = { f2bf(v.x), f2bf(v.y), f2bf(v.z), f2bf(v.w) };
        *(u16x4*)&out[i] = w;
    }
}

// ---------------------------------------------------------------------------
// Transpose + convert: in [R][C] f32  ->  out [C][R] bf16 (out pitch = R).
// ---------------------------------------------------------------------------
__global__ __launch_bounds__(256) void transpose_cvt_kernel(
    const float* __restrict__ in, u16* __restrict__ out, int R, int C)
{
    __shared__ u16 tile[64][65];
    const int r0 = blockIdx.y*64, c0 = blockIdx.x*64;
    const int tr = threadIdx.x >> 4;          // 0..15
    const int tc = (threadIdx.x & 15) * 4;    // 0,4,..60
    #pragma unroll
    for (int i = 0; i < 4; i++) {
        const int r = tr + i*16;
        float4 v = *(const float4*)&in[(size_t)(r0 + r)*C + c0 + tc];
        tile[tc+0][r] = f2bf(v.x);
        tile[tc+1][r] = f2bf(v.y);
        tile[tc+2][r] = f2bf(v.z);
        tile[tc+3][r] = f2bf(v.w);
    }
    __syncthreads();
    #pragma unroll
    for (int i = 0; i < 4; i++) {
        const int c = tr + i*16;
        u16x4 w = { tile[c][tc+0], tile[c][tc+1], tile[c][tc+2], tile[c][tc+3] };
        *(u16x4*)&out[(size_t)(c0 + c)*R + r0 + tc] = w;
    }
}

// ---------------------------------------------------------------------------
// bf16 transpose of the V segment of the merged qkv buffer:
//   in:  qkv[(b*T+t)*QKVP + VOFF + kvh*HD_ + d]
//   out: vt[((b*KV_+kvh)*HD_ + d)*T_ + t]
// ---------------------------------------------------------------------------
__global__ __launch_bounds__(256) void transpose_v_kernel(
    const u16* __restrict__ qkv, u16* __restrict__ vt)
{
    __shared__ u16 tile[64][65];
    const int t0 = blockIdx.x*64;
    const int d0 = blockIdx.y*64;              // 0 or 64
    const int bk = blockIdx.z;                 // b*KV_+kvh
    const int tr = threadIdx.x >> 4;           // 0..15
    const int tc = (threadIdx.x & 15) * 4;     // 0,4,..60
    #pragma unroll
    for (int i = 0; i < 4; i++) {
        const int t = t0 + tr + i*16;
        u16x4 v = *(const u16x4*)&qkv[(size_t)((bk>>2)*T_ + t)*QKVP + VOFF
                                      + (bk&3)*HD_ + d0 + tc];
        tile[tc+0][tr+i*16] = v[0];
        tile[tc+1][tr+i*16] = v[1];
        tile[tc+2][tr+i*16] = v[2];
        tile[tc+3][tr+i*16] = v[3];
    }
    __syncthreads();
    #pragma unroll
    for (int i = 0; i < 4; i++) {
        const int d = tr + i*16;
        u16x4 w = { tile[d][tc+0], tile[d][tc+1], tile[d][tc+2], tile[d][tc+3] };
        *(u16x4*)&vt[((size_t)bk*HD_ + d0 + d)*T_ + t0 + tc] = w;
    }
}

// ---------------------------------------------------------------------------
// m97-style MFMA GEMM with pitches: C[.,N] = A @ Bt^T, bf16 in, f32 acc.
// 128x128 tile, BK=32, 256 threads (4 waves, 2x2 quadrants of 64x64).
// ---------------------------------------------------------------------------
#define GBM 128
#define GBN 128
#define GBK 32

template<bool OUT_BF16>
__global__ __launch_bounds__(256) void gemm_mfma_kernel(
    const u16* __restrict__ A, const u16* __restrict__ Bt,
    void* __restrict__ C, int N, int K, int lda, int ldb, int ldc)
{
    __shared__ __align__(16) u16 As[GBM][GBK];
    __shared__ __align__(16) u16 Bs[GBN][GBK];
    const int tid  = threadIdx.x;
    const int lane = tid & 63;
    const int wave = tid >> 6;
    const int l15  = lane & 15;
    const int quad = lane >> 4;
    const int wr   = (wave >> 1) * 64;
    const int wc   = (wave & 1) * 64;
    const size_t row0 = (size_t)blockIdx.y * GBM;
    const size_t col0 = (size_t)blockIdx.x * GBN;

    f32x4 acc[4][4];
    #pragma unroll
    for (int i = 0; i < 4; i++)
        #pragma unroll
        for (int j = 0; j < 4; j++)
            acc[i][j] = (f32x4){0.f,0.f,0.f,0.f};

    for (int k0 = 0; k0 < K; k0 += GBK) {
        #pragma unroll
        for (int c = 0; c < 2; c++) {
            const int e = (c*256 + tid) * 8;
            const int r = e >> 5, cc = e & 31;
            async_copy16(A  + (row0 + r)*lda + k0 + cc, &As[r][cc]);
            async_copy16(Bt + (col0 + r)*ldb + k0 + cc, &Bs[r][cc]);
        }
        __syncthreads();

        short8 af[4], bf[4];
        #pragma unroll
        for (int i = 0; i < 4; i++)
            af[i] = *(const short8*)&As[wr + i*16 + l15][quad*8];
        #pragma unroll
        for (int j = 0; j < 4; j++)
            bf[j] = *(const short8*)&Bs[wc + j*16 + l15][quad*8];
        #pragma unroll
        for (int i = 0; i < 4; i++)
            #pragma unroll
            for (int j = 0; j < 4; j++)
                acc[i][j] = __builtin_amdgcn_mfma_f32_16x16x32_bf16(
                    af[i], bf[j], acc[i][j], 0, 0, 0);
        __syncthreads();
    }

    #pragma unroll
    for (int i = 0; i < 4; i++)
        #pragma unroll
        for (int r = 0; r < 4; r++) {
            const size_t row = row0 + wr + i*16 + quad*4 + r;
            #pragma unroll
            for (int j = 0; j < 4; j++) {
                const size_t col = col0 + wc + j*16 + l15;
                if (OUT_BF16) ((u16*)C)[row*ldc + col] = f2bf(acc[i][j][r]);
                else          ((float*)C)[row*ldc + col] = acc[i][j][r];
            }
        }
}

// ---------------------------------------------------------------------------
// Fused RMSNorm + RoPE, in place on bf16 rows inside the pitched qkv buffer.
// post_scale folds 1/sqrt(HD) into q rows (1.0 for k rows).
// ---------------------------------------------------------------------------
__global__ __launch_bounds__(128) void rmsnorm_rope_kernel(
    u16* __restrict__ qk, const float* __restrict__ scale,
    const float* __restrict__ cosT, const float* __restrict__ sinT,
    int heads_per_token, int head_off, float post_scale)
{
    const int row   = blockIdx.x;
    const int d     = threadIdx.x;
    const int token = row / heads_per_token;
    const int hidx  = row % heads_per_token;
    const int t     = token % T_;
    u16* p = qk + (size_t)token*QKVP + head_off + hidx*HD_;

    float v = bf2f(p[d]);
    __shared__ float red[HD_];
    __shared__ float xs[HD_];
    red[d] = v*v;
    __syncthreads();
    #pragma unroll
    for (int s = 64; s > 0; s >>= 1) {
        if (d < s) red[d] += red[d + s];
        __syncthreads();
    }
    const float rms = rsqrtf(red[0] * (1.0f/HD_) + EPS_);
    const float xn  = v * rms * scale[d];
    xs[d] = xn;
    __syncthreads();
    const float part = xs[d ^ 1];
    const float rot  = (d & 1) ? part : -part;
    p[d] = f2bf((xn*cosT[(size_t)t*HD_ + d] + rot*sinT[(size_t)t*HD_ + d]) * post_scale);
}

// ---------------------------------------------------------------------------
// Flash-style causal GQA attention v3.
//  - Q A-fragments held in REGISTERS (16 VGPR/lane), no Q LDS, no Q barrier.
//  - LDS = K 16KB + V^T 16KB + P 8KB = 40KB -> 4 blocks/CU.
//  - BKV=64 keys/tile, 2 barriers/tile, in-register online softmax.
//  - 1/sqrt(HD) pre-folded into q; causal mask only on the diagonal tile.
// O written in-place into the q segment of qkv (disjoint from k/v segments).
// ---------------------------------------------------------------------------
#define BQ  64
#define BKV 64

__global__ __launch_bounds__(256) void attn_mfma3_kernel(
    const u16* __restrict__ qkv, const u16* __restrict__ Vtg)
{
    __shared__ __align__(16) u16 Ks[16][BKV][8];   // [k-chunk][key][8]    16 KB
    __shared__ __align__(16) u16 Vt[8][HD_][8];    // [key-chunk][d][8]    16 KB
    __shared__ __align__(16) u16 Pb[4][8][16][8];  // [wave][key-chunk][row][8] 8 KB

    const int qt   = (gridDim.x - 1) - blockIdx.x;   // heavy (long-causal) first
    const int h    = blockIdx.y;
    const int b    = blockIdx.z;
    const int q0   = qt * BQ;
    const int kvh  = h >> 2;                          // H_/KV_ = 4
    const int tid  = threadIdx.x;
    const int lane = tid & 63;
    const int wave = tid >> 6;
    const int l15  = lane & 15;
    const int quad = lane >> 4;

    // ---- Q A-fragments straight to registers (row = wave*16+l15) ----
    short8 qf[4];
    {
        const u16* qbase = qkv + (size_t)(b*T_ + q0 + wave*16 + l15)*QKVP + h*HD_;
        #pragma unroll
        for (int kt = 0; kt < 4; kt++)
            qf[kt] = *(const short8*)(qbase + (kt*4 + quad)*8);
    }

    float m_r[4] = {-INFINITY,-INFINITY,-INFINITY,-INFINITY};
    float l_r[4] = {0.f,0.f,0.f,0.f};
    f32x4 oacc[8];
    #pragma unroll
    for (int cv = 0; cv < 8; cv++) oacc[cv] = (f32x4){0.f,0.f,0.f,0.f};

    const int ntiles = qt + 1;
    for (int t = 0; t < ntiles; t++) {
        const int k0 = t * BKV;
        __syncthreads();        // all waves done reading prev K/V tiles

        // ---- stage K tile [16cc][64key] from k segment ----
        #pragma unroll
        for (int it = 0; it < 4; it++) {
            const int n   = it*256 + tid;
            const int cc  = n >> 6;
            const int key = n & 63;
            async_copy16(qkv + (size_t)(b*T_ + k0 + key)*QKVP + KOFF + kvh*HD_ + cc*8,
                         &Ks[cc][key][0]);
        }
        // ---- stage V^T tile [8cc][128d] ----
        #pragma unroll
        for (int it = 0; it < 4; it++) {
            const int n  = it*256 + tid;
            const int cc = n >> 7;
            const int d  = n & 127;
            async_copy16(Vtg + ((size_t)(b*KV_ + kvh)*HD_ + d)*T_ + k0 + cc*8,
                         &Vt[cc][d][0]);
        }
        __syncthreads();        // drains vmcnt(0): staged data visible

        // ---- S = Q @ K^T : wave slab (16 rows) x 64 keys ----
        f32x4 s[4];
        #pragma unroll
        for (int c = 0; c < 4; c++) s[c] = (f32x4){0.f,0.f,0.f,0.f};
        #pragma unroll
        for (int kt = 0; kt < 4; kt++) {
            #pragma unroll
            for (int c = 0; c < 4; c++) {
                short8 bf = *(const short8*)&Ks[kt*4 + quad][c*16 + l15][0];
                s[c] = __builtin_amdgcn_mfma_f32_16x16x32_bf16(qf[kt], bf, s[c], 0, 0, 0);
            }
        }

        // ---- in-register online softmax (C-layout: row=quad*4+r, col=c*16+l15) ----
        const int qrow0 = q0 + wave*16 + quad*4;
        float alpha[4];
        const bool diag = (t == ntiles - 1);
        #pragma unroll
        for (int r = 0; r < 4; r++) {
            if (diag) {
                #pragma unroll
                for (int c = 0; c < 4; c++) {
                    const int key = k0 + c*16 + l15;
                    if (key > qrow0 + r) s[c][r] = -1e30f;
                }
            }
            float mloc = fmaxf(fmaxf(s[0][r], s[1][r]), fmaxf(s[2][r], s[3][r]));
            #pragma unroll
            for (int off = 1; off < 16; off <<= 1)
                mloc = fmaxf(mloc, __shfl_xor(mloc, off, 16));
            const float mn = fmaxf(m_r[r], mloc);
            alpha[r] = __expf(m_r[r] - mn);
            m_r[r] = mn;
            float lad = 0.f;
            #pragma unroll
            for (int c = 0; c < 4; c++) {
                const float p = __expf(s[c][r] - mn);
                s[c][r] = p;
                lad += p;
            }
            #pragma unroll
            for (int off = 1; off < 16; off <<= 1)
                lad += __shfl_xor(lad, off, 16);
            l_r[r] = alpha[r]*l_r[r] + lad;
        }

        // ---- P -> wave-private LDS (A-operand layout), no barrier needed ----
        #pragma unroll
        for (int r = 0; r < 4; r++)
            #pragma unroll
            for (int c = 0; c < 4; c++)
                Pb[wave][c*2 + (l15 >> 3)][quad*4 + r][l15 & 7] = f2bf(s[c][r]);

        // ---- rescale O, then O += P @ V ----
        #pragma unroll
        for (int cv = 0; cv < 8; cv++)
            #pragma unroll
            for (int r = 0; r < 4; r++)
                oacc[cv][r] *= alpha[r];

        #pragma unroll
        for (int kt2 = 0; kt2 < 2; kt2++) {
            short8 a = *(const short8*)&Pb[wave][kt2*4 + quad][l15][0];
            #pragma unroll
            for (int cv = 0; cv < 8; cv++) {
                short8 vf = *(const short8*)&Vt[kt2*4 + quad][cv*16 + l15][0];
                oacc[cv] = __builtin_amdgcn_mfma_f32_16x16x32_bf16(a, vf, oacc[cv], 0, 0, 0);
            }
        }
    }

    // ---- epilogue: O / l -> q segment in place ----
    #pragma unroll
    for (int r = 0; r < 4; r++) {
        const float linv = 1.0f / l_r[r];
        u16* orow = (u16*)qkv + (size_t)(b*T_ + q0 + wave*16 + quad*4 + r)*QKVP
                    + h*HD_ + l15;
        #pragma unroll
        for (int cv = 0; cv < 8; cv++)
            orow[cv*16] = f2bf(oacc[cv][r] * linv);
    }
}

// ---------------------------------------------------------------------------
extern "C" void kernel_launch(void* const* d_in, const int* in_sizes, int n_in,
                              void* d_out, int out_size, void* d_ws, size_t ws_size,
                              hipStream_t stream)
{
    const float* x    = (const float*)d_in[0];   // [B,T,D]
    const float* Wq   = (const float*)d_in[1];   // [D, H*HD]
    const float* Wk   = (const float*)d_in[2];   // [D, KV*HD]
    const float* Wv   = (const float*)d_in[3];   // [D, KV*HD]
    const float* Wo   = (const float*)d_in[4];   // [H*HD, D]
    const float* qsc  = (const float*)d_in[5];   // [HD]
    const float* ksc  = (const float*)d_in[6];   // [HD]
    const float* cosT = (const float*)d_in[7];   // [T, HD]
    const float* sinT = (const float*)d_in[8];   // [T, HD]
    float* out = (float*)d_out;

    // Workspace carve (bf16, ~67 MB total)
    u16* xb     = (u16*)d_ws;                      // [BT, 2048]
    u16* Wqkvt  = xb    + (size_t)BT_*D_;          // [3072, 2048]
    u16* Wot    = Wqkvt + (size_t)QKVP*D_;         // [2048, 2048]
    u16* qkv    = Wot   + (size_t)D_*(H_*HD_);     // [BT, 3072]
    u16* vtg    = qkv   + (size_t)BT_*QKVP;        // [B*KV, HD, T]

    // ---- convert x; transpose+convert weights (concatenated qkv weight) ----
    cvt_f32_bf16_kernel<<<(BT_*D_)/1024, 256, 0, stream>>>(x, xb, BT_*D_);
    transpose_cvt_kernel<<<dim3((H_*HD_)/64,  D_/64), 256, 0, stream>>>(
        Wq, Wqkvt, D_, H_*HD_);
    transpose_cvt_kernel<<<dim3((KV_*HD_)/64, D_/64), 256, 0, stream>>>(
        Wk, Wqkvt + (size_t)KOFF*D_, D_, KV_*HD_);
    transpose_cvt_kernel<<<dim3((KV_*HD_)/64, D_/64), 256, 0, stream>>>(
        Wv, Wqkvt + (size_t)VOFF*D_, D_, KV_*HD_);
    transpose_cvt_kernel<<<dim3(D_/64, (H_*HD_)/64),  256, 0, stream>>>(
        Wo, Wot, H_*HD_, D_);

    // ---- merged q|k|v projection: [4096,2048] x [2048,3072] ----
    gemm_mfma_kernel<true><<<dim3(QKVP/GBN, BT_/GBM), 256, 0, stream>>>(
        xb, Wqkvt, qkv, QKVP, D_, D_, D_, QKVP);

    // ---- RMSNorm + RoPE in place (q gets 1/sqrt(HD) folded in) ----
    rmsnorm_rope_kernel<<<BT_*H_,  HD_, 0, stream>>>(
        qkv, qsc, cosT, sinT, H_, 0, 0.08838834764831845f);
    rmsnorm_rope_kernel<<<BT_*KV_, HD_, 0, stream>>>(
        qkv, ksc, cosT, sinT, KV_, KOFF, 1.0f);

    // ---- V^T into global [b*KV][d][t] ----
    transpose_v_kernel<<<dim3(T_/64, HD_/64, B_*KV_), 256, 0, stream>>>(qkv, vtg);

    // ---- Flash attention v3 (O in-place into q segment) ----
    attn_mfma3_kernel<<<dim3(T_/BQ, H_, B_), 256, 0, stream>>>(qkv, vtg);

    // ---- out = attn @ Wo (f32 out): A = q segment, pitch 3072 ----
    gemm_mfma_kernel<false><<<dim3(D_/GBN, BT_/GBM), 256, 0, stream>>>(
        qkv, Wot, out, D_, D_, QKVP, D_, D_);
}

// Round 7
// 454.412 us; speedup vs baseline: 1.4081x; 1.4081x over previous
//
#include <hip/hip_runtime.h>
#include <hip/hip_bf16.h>

// Problem constants (from reference)
#define B_   2
#define T_   2048
#define D_   2048
#define H_   16
#define KV_  4
#define HD_  128
#define BT_  (B_*T_)         // 4096 token rows
#define QKVP 3072            // per-token pitch of merged [q|k|v] buffer
#define KOFF 2048            // k segment offset within a token row
#define VOFF 2560            // v segment offset within a token row
static constexpr float EPS_ = 1e-6f;

typedef unsigned short u16;
typedef __attribute__((ext_vector_type(8))) short short8;          // 8 bf16 = 16 B
typedef __attribute__((ext_vector_type(4))) float f32x4;           // MFMA acc
typedef __attribute__((ext_vector_type(4))) unsigned short u16x4;  // 8 B

__device__ __forceinline__ u16 f2bf(float f){
    unsigned u = __float_as_uint(f);
    u += 0x7FFF + ((u >> 16) & 1);          // round-to-nearest-even
    return (u16)(u >> 16);
}
__device__ __forceinline__ float bf2f(u16 u){
    return __uint_as_float((unsigned)u << 16);
}

// Async global->LDS, 16 B per lane. LDS dest must be wave-uniform base + lane*16.
__device__ __forceinline__ void async_copy16(const void* g, void* l) {
    __builtin_amdgcn_global_load_lds(
        (const __attribute__((address_space(1))) unsigned int*)g,
        (__attribute__((address_space(3))) unsigned int*)l, 16, 0, 0);
}

// ---------------------------------------------------------------------------
// f32 -> bf16 elementwise convert (n % 4 == 0)
// ---------------------------------------------------------------------------
__global__ __launch_bounds__(256) void cvt_f32_bf16_kernel(
    const float* __restrict__ in, u16* __restrict__ out, int n)
{
    const int i = (blockIdx.x*256 + threadIdx.x)*4;
    if (i < n) {
        float4 v = *(const float4*)&in[i];
        u16x4 w = { f2bf(v.x), f2bf(v.y), f2bf(v.z), f2bf(v.w) };
        *(u16x4*)&out[i] = w;
    }
}

// ---------------------------------------------------------------------------
// Transpose + convert: in [R][C] f32  ->  out [C][R] bf16 (out pitch = R).
// ---------------------------------------------------------------------------
__global__ __launch_bounds__(256) void transpose_cvt_kernel(
    const float* __restrict__ in, u16* __restrict__ out, int R, int C)
{
    __shared__ u16 tile[64][65];
    const int r0 = blockIdx.y*64, c0 = blockIdx.x*64;
    const int tr = threadIdx.x >> 4;          // 0..15
    const int tc = (threadIdx.x & 15) * 4;    // 0,4,..60
    #pragma unroll
    for (int i = 0; i < 4; i++) {
        const int r = tr + i*16;
        float4 v = *(const float4*)&in[(size_t)(r0 + r)*C + c0 + tc];
        tile[tc+0][r] = f2bf(v.x);
        tile[tc+1][r] = f2bf(v.y);
        tile[tc+2][r] = f2bf(v.z);
        tile[tc+3][r] = f2bf(v.w);
    }
    __syncthreads();
    #pragma unroll
    for (int i = 0; i < 4; i++) {
        const int c = tr + i*16;
        u16x4 w = { tile[c][tc+0], tile[c][tc+1], tile[c][tc+2], tile[c][tc+3] };
        *(u16x4*)&out[(size_t)(c0 + c)*R + r0 + tc] = w;
    }
}

// ---------------------------------------------------------------------------
// bf16 transpose of the V segment of the merged qkv buffer:
//   in:  qkv[(b*T+t)*QKVP + VOFF + kvh*HD_ + d]
//   out: vt[((b*KV_+kvh)*HD_ + d)*T_ + t]
// ---------------------------------------------------------------------------
__global__ __launch_bounds__(256) void transpose_v_kernel(
    const u16* __restrict__ qkv, u16* __restrict__ vt)
{
    __shared__ u16 tile[64][65];
    const int t0 = blockIdx.x*64;
    const int d0 = blockIdx.y*64;              // 0 or 64
    const int bk = blockIdx.z;                 // b*KV_+kvh
    const int tr = threadIdx.x >> 4;           // 0..15
    const int tc = (threadIdx.x & 15) * 4;     // 0,4,..60
    #pragma unroll
    for (int i = 0; i < 4; i++) {
        const int t = t0 + tr + i*16;
        u16x4 v = *(const u16x4*)&qkv[(size_t)((bk>>2)*T_ + t)*QKVP + VOFF
                                      + (bk&3)*HD_ + d0 + tc];
        tile[tc+0][tr+i*16] = v[0];
        tile[tc+1][tr+i*16] = v[1];
        tile[tc+2][tr+i*16] = v[2];
        tile[tc+3][tr+i*16] = v[3];
    }
    __syncthreads();
    #pragma unroll
    for (int i = 0; i < 4; i++) {
        const int d = tr + i*16;
        u16x4 w = { tile[d][tc+0], tile[d][tc+1], tile[d][tc+2], tile[d][tc+3] };
        *(u16x4*)&vt[((size_t)bk*HD_ + d0 + d)*T_ + t0 + tc] = w;
    }
}

// ---------------------------------------------------------------------------
// m97-style MFMA GEMM with pitches: C[.,N] = A @ Bt^T, bf16 in, f32 acc.
// 128x128 tile, BK=32, 256 threads (4 waves, 2x2 quadrants of 64x64).
// ---------------------------------------------------------------------------
#define GBM 128
#define GBN 128
#define GBK 32

template<bool OUT_BF16>
__global__ __launch_bounds__(256) void gemm_mfma_kernel(
    const u16* __restrict__ A, const u16* __restrict__ Bt,
    void* __restrict__ C, int N, int K, int lda, int ldb, int ldc)
{
    __shared__ __align__(16) u16 As[GBM][GBK];
    __shared__ __align__(16) u16 Bs[GBN][GBK];
    const int tid  = threadIdx.x;
    const int lane = tid & 63;
    const int wave = tid >> 6;
    const int l15  = lane & 15;
    const int quad = lane >> 4;
    const int wr   = (wave >> 1) * 64;
    const int wc   = (wave & 1) * 64;
    const size_t row0 = (size_t)blockIdx.y * GBM;
    const size_t col0 = (size_t)blockIdx.x * GBN;

    f32x4 acc[4][4];
    #pragma unroll
    for (int i = 0; i < 4; i++)
        #pragma unroll
        for (int j = 0; j < 4; j++)
            acc[i][j] = (f32x4){0.f,0.f,0.f,0.f};

    for (int k0 = 0; k0 < K; k0 += GBK) {
        #pragma unroll
        for (int c = 0; c < 2; c++) {
            const int e = (c*256 + tid) * 8;
            const int r = e >> 5, cc = e & 31;
            async_copy16(A  + (row0 + r)*lda + k0 + cc, &As[r][cc]);
            async_copy16(Bt + (col0 + r)*ldb + k0 + cc, &Bs[r][cc]);
        }
        __syncthreads();

        short8 af[4], bf[4];
        #pragma unroll
        for (int i = 0; i < 4; i++)
            af[i] = *(const short8*)&As[wr + i*16 + l15][quad*8];
        #pragma unroll
        for (int j = 0; j < 4; j++)
            bf[j] = *(const short8*)&Bs[wc + j*16 + l15][quad*8];
        #pragma unroll
        for (int i = 0; i < 4; i++)
            #pragma unroll
            for (int j = 0; j < 4; j++)
                acc[i][j] = __builtin_amdgcn_mfma_f32_16x16x32_bf16(
                    af[i], bf[j], acc[i][j], 0, 0, 0);
        __syncthreads();
    }

    #pragma unroll
    for (int i = 0; i < 4; i++)
        #pragma unroll
        for (int r = 0; r < 4; r++) {
            const size_t row = row0 + wr + i*16 + quad*4 + r;
            #pragma unroll
            for (int j = 0; j < 4; j++) {
                const size_t col = col0 + wc + j*16 + l15;
                if (OUT_BF16) ((u16*)C)[row*ldc + col] = f2bf(acc[i][j][r]);
                else          ((float*)C)[row*ldc + col] = acc[i][j][r];
            }
        }
}

// ---------------------------------------------------------------------------
// Fused RMSNorm + RoPE, in place on bf16 rows inside the pitched qkv buffer.
// post_scale folds 1/sqrt(HD) into q rows (1.0 for k rows).
// ---------------------------------------------------------------------------
__global__ __launch_bounds__(128) void rmsnorm_rope_kernel(
    u16* __restrict__ qk, const float* __restrict__ scale,
    const float* __restrict__ cosT, const float* __restrict__ sinT,
    int heads_per_token, int head_off, float post_scale)
{
    const int row   = blockIdx.x;
    const int d     = threadIdx.x;
    const int token = row / heads_per_token;
    const int hidx  = row % heads_per_token;
    const int t     = token % T_;
    u16* p = qk + (size_t)token*QKVP + head_off + hidx*HD_;

    float v = bf2f(p[d]);
    __shared__ float red[HD_];
    __shared__ float xs[HD_];
    red[d] = v*v;
    __syncthreads();
    #pragma unroll
    for (int s = 64; s > 0; s >>= 1) {
        if (d < s) red[d] += red[d + s];
        __syncthreads();
    }
    const float rms = rsqrtf(red[0] * (1.0f/HD_) + EPS_);
    const float xn  = v * rms * scale[d];
    xs[d] = xn;
    __syncthreads();
    const float part = xs[d ^ 1];
    const float rot  = (d & 1) ? part : -part;
    p[d] = f2bf((xn*cosT[(size_t)t*HD_ + d] + rot*sinT[(size_t)t*HD_ + d]) * post_scale);
}

// ---------------------------------------------------------------------------
// Flash-style causal GQA attention v3b.
//  - Q A-fragments in registers; __launch_bounds__(256,4) caps VGPR at 128
//    (round 6 lesson: 132 VGPR crossed the 128 granule -> occupancy halved).
//  - LDS = K 16KB + V^T 16KB + P 8KB = 40KB -> 4 blocks/CU.
//  - BKV=64 keys/tile, 2 barriers/tile, in-register online softmax.
//  - 1/sqrt(HD) pre-folded into q; causal mask only on the diagonal tile.
// O written in-place into the q segment of qkv (disjoint from k/v segments).
// ---------------------------------------------------------------------------
#define BQ  64
#define BKV 64

__global__ __launch_bounds__(256, 4) void attn_mfma3_kernel(
    const u16* __restrict__ qkv, const u16* __restrict__ Vtg)
{
    __shared__ __align__(16) u16 Ks[16][BKV][8];   // [k-chunk][key][8]    16 KB
    __shared__ __align__(16) u16 Vt[8][HD_][8];    // [key-chunk][d][8]    16 KB
    __shared__ __align__(16) u16 Pb[4][8][16][8];  // [wave][key-chunk][row][8] 8 KB

    const int qt   = (gridDim.x - 1) - blockIdx.x;   // heavy (long-causal) first
    const int h    = blockIdx.y;
    const int b    = blockIdx.z;
    const int q0   = qt * BQ;
    const int kvh  = h >> 2;                          // H_/KV_ = 4
    const int tid  = threadIdx.x;
    const int lane = tid & 63;
    const int wave = tid >> 6;
    const int l15  = lane & 15;
    const int quad = lane >> 4;

    // ---- Q A-fragments straight to registers (row = wave*16+l15) ----
    short8 qf[4];
    {
        const u16* qbase = qkv + (size_t)(b*T_ + q0 + wave*16 + l15)*QKVP + h*HD_;
        #pragma unroll
        for (int kt = 0; kt < 4; kt++)
            qf[kt] = *(const short8*)(qbase + (kt*4 + quad)*8);
    }

    float m_r[4] = {-INFINITY,-INFINITY,-INFINITY,-INFINITY};
    float l_r[4] = {0.f,0.f,0.f,0.f};
    f32x4 oacc[8];
    #pragma unroll
    for (int cv = 0; cv < 8; cv++) oacc[cv] = (f32x4){0.f,0.f,0.f,0.f};

    const int ntiles = qt + 1;
    for (int t = 0; t < ntiles; t++) {
        const int k0 = t * BKV;
        __syncthreads();        // all waves done reading prev K/V tiles

        // ---- stage K tile [16cc][64key] from k segment ----
        #pragma unroll
        for (int it = 0; it < 4; it++) {
            const int n   = it*256 + tid;
            const int cc  = n >> 6;
            const int key = n & 63;
            async_copy16(qkv + (size_t)(b*T_ + k0 + key)*QKVP + KOFF + kvh*HD_ + cc*8,
                         &Ks[cc][key][0]);
        }
        // ---- stage V^T tile [8cc][128d] ----
        #pragma unroll
        for (int it = 0; it < 4; it++) {
            const int n  = it*256 + tid;
            const int cc = n >> 7;
            const int d  = n & 127;
            async_copy16(Vtg + ((size_t)(b*KV_ + kvh)*HD_ + d)*T_ + k0 + cc*8,
                         &Vt[cc][d][0]);
        }
        __syncthreads();        // drains vmcnt(0): staged data visible

        // ---- S = Q @ K^T : wave slab (16 rows) x 64 keys ----
        f32x4 s[4];
        #pragma unroll
        for (int c = 0; c < 4; c++) s[c] = (f32x4){0.f,0.f,0.f,0.f};
        #pragma unroll
        for (int kt = 0; kt < 4; kt++) {
            #pragma unroll
            for (int c = 0; c < 4; c++) {
                short8 bf = *(const short8*)&Ks[kt*4 + quad][c*16 + l15][0];
                s[c] = __builtin_amdgcn_mfma_f32_16x16x32_bf16(qf[kt], bf, s[c], 0, 0, 0);
            }
        }

        // ---- in-register online softmax (C-layout: row=quad*4+r, col=c*16+l15) ----
        const int qrow0 = q0 + wave*16 + quad*4;
        float alpha[4];
        const bool diag = (t == ntiles - 1);
        #pragma unroll
        for (int r = 0; r < 4; r++) {
            if (diag) {
                #pragma unroll
                for (int c = 0; c < 4; c++) {
                    const int key = k0 + c*16 + l15;
                    if (key > qrow0 + r) s[c][r] = -1e30f;
                }
            }
            float mloc = fmaxf(fmaxf(s[0][r], s[1][r]), fmaxf(s[2][r], s[3][r]));
            #pragma unroll
            for (int off = 1; off < 16; off <<= 1)
                mloc = fmaxf(mloc, __shfl_xor(mloc, off, 16));
            const float mn = fmaxf(m_r[r], mloc);
            alpha[r] = __expf(m_r[r] - mn);
            m_r[r] = mn;
            float lad = 0.f;
            #pragma unroll
            for (int c = 0; c < 4; c++) {
                const float p = __expf(s[c][r] - mn);
                s[c][r] = p;
                lad += p;
            }
            #pragma unroll
            for (int off = 1; off < 16; off <<= 1)
                lad += __shfl_xor(lad, off, 16);
            l_r[r] = alpha[r]*l_r[r] + lad;
        }

        // ---- P -> wave-private LDS (A-operand layout), no barrier needed ----
        #pragma unroll
        for (int r = 0; r < 4; r++)
            #pragma unroll
            for (int c = 0; c < 4; c++)
                Pb[wave][c*2 + (l15 >> 3)][quad*4 + r][l15 & 7] = f2bf(s[c][r]);

        // ---- rescale O, then O += P @ V ----
        #pragma unroll
        for (int cv = 0; cv < 8; cv++)
            #pragma unroll
            for (int r = 0; r < 4; r++)
                oacc[cv][r] *= alpha[r];

        #pragma unroll
        for (int kt2 = 0; kt2 < 2; kt2++) {
            short8 a = *(const short8*)&Pb[wave][kt2*4 + quad][l15][0];
            #pragma unroll
            for (int cv = 0; cv < 8; cv++) {
                short8 vf = *(const short8*)&Vt[kt2*4 + quad][cv*16 + l15][0];
                oacc[cv] = __builtin_amdgcn_mfma_f32_16x16x32_bf16(a, vf, oacc[cv], 0, 0, 0);
            }
        }
    }

    // ---- epilogue: O / l -> q segment in place ----
    #pragma unroll
    for (int r = 0; r < 4; r++) {
        const float linv = 1.0f / l_r[r];
        u16* orow = (u16*)qkv + (size_t)(b*T_ + q0 + wave*16 + quad*4 + r)*QKVP
                    + h*HD_ + l15;
        #pragma unroll
        for (int cv = 0; cv < 8; cv++)
            orow[cv*16] = f2bf(oacc[cv][r] * linv);
    }
}

// ---------------------------------------------------------------------------
extern "C" void kernel_launch(void* const* d_in, const int* in_sizes, int n_in,
                              void* d_out, int out_size, void* d_ws, size_t ws_size,
                              hipStream_t stream)
{
    const float* x    = (const float*)d_in[0];   // [B,T,D]
    const float* Wq   = (const float*)d_in[1];   // [D, H*HD]
    const float* Wk   = (const float*)d_in[2];   // [D, KV*HD]
    const float* Wv   = (const float*)d_in[3];   // [D, KV*HD]
    const float* Wo   = (const float*)d_in[4];   // [H*HD, D]
    const float* qsc  = (const float*)d_in[5];   // [HD]
    const float* ksc  = (const float*)d_in[6];   // [HD]
    const float* cosT = (const float*)d_in[7];   // [T, HD]
    const float* sinT = (const float*)d_in[8];   // [T, HD]
    float* out = (float*)d_out;

    // Workspace carve (bf16, ~67 MB total)
    u16* xb     = (u16*)d_ws;                      // [BT, 2048]
    u16* Wqkvt  = xb    + (size_t)BT_*D_;          // [3072, 2048]
    u16* Wot    = Wqkvt + (size_t)QKVP*D_;         // [2048, 2048]
    u16* qkv    = Wot   + (size_t)D_*(H_*HD_);     // [BT, 3072]
    u16* vtg    = qkv   + (size_t)BT_*QKVP;        // [B*KV, HD, T]

    // ---- convert x; transpose+convert weights (concatenated qkv weight) ----
    cvt_f32_bf16_kernel<<<(BT_*D_)/1024, 256, 0, stream>>>(x, xb, BT_*D_);
    transpose_cvt_kernel<<<dim3((H_*HD_)/64,  D_/64), 256, 0, stream>>>(
        Wq, Wqkvt, D_, H_*HD_);
    transpose_cvt_kernel<<<dim3((KV_*HD_)/64, D_/64), 256, 0, stream>>>(
        Wk, Wqkvt + (size_t)KOFF*D_, D_, KV_*HD_);
    transpose_cvt_kernel<<<dim3((KV_*HD_)/64, D_/64), 256, 0, stream>>>(
        Wv, Wqkvt + (size_t)VOFF*D_, D_, KV_*HD_);
    transpose_cvt_kernel<<<dim3(D_/64, (H_*HD_)/64),  256, 0, stream>>>(
        Wo, Wot, H_*HD_, D_);

    // ---- merged q|k|v projection: [4096,2048] x [2048,3072] ----
    gemm_mfma_kernel<true><<<dim3(QKVP/GBN, BT_/GBM), 256, 0, stream>>>(
        xb, Wqkvt, qkv, QKVP, D_, D_, D_, QKVP);

    // ---- RMSNorm + RoPE in place (q gets 1/sqrt(HD) folded in) ----
    rmsnorm_rope_kernel<<<BT_*H_,  HD_, 0, stream>>>(
        qkv, qsc, cosT, sinT, H_, 0, 0.08838834764831845f);
    rmsnorm_rope_kernel<<<BT_*KV_, HD_, 0, stream>>>(
        qkv, ksc, cosT, sinT, KV_, KOFF, 1.0f);

    // ---- V^T into global [b*KV][d][t] ----
    transpose_v_kernel<<<dim3(T_/64, HD_/64, B_*KV_), 256, 0, stream>>>(qkv, vtg);

    // ---- Flash attention v3b (O in-place into q segment) ----
    attn_mfma3_kernel<<<dim3(T_/BQ, H_, B_), 256, 0, stream>>>(qkv, vtg);

    // ---- out = attn @ Wo (f32 out): A = q segment, pitch 3072 ----
    gemm_mfma_kernel<false><<<dim3(D_/GBN, BT_/GBM), 256, 0, stream>>>(
        qkv, Wot, out, D_, D_, QKVP, D_, D_);
}

// Round 8
// 398.640 us; speedup vs baseline: 1.6051x; 1.1399x over previous
//
#include <hip/hip_runtime.h>
#include <hip/hip_bf16.h>

// Problem constants (from reference)
#define B_   2
#define T_   2048
#define D_   2048
#define H_   16
#define KV_  4
#define HD_  128
#define BT_  (B_*T_)         // 4096 token rows
#define QKVP 3072            // per-token pitch of merged [q|k|v] buffer
#define KOFF 2048            // k segment offset within a token row
#define VOFF 2560            // v segment offset within a token row
static constexpr float EPS_ = 1e-6f;

typedef unsigned short u16;
typedef __attribute__((ext_vector_type(8))) short short8;          // 8 bf16 = 16 B
typedef __attribute__((ext_vector_type(4))) float f32x4;           // MFMA acc
typedef __attribute__((ext_vector_type(4))) unsigned short u16x4;  // 8 B

__device__ __forceinline__ u16 f2bf(float f){
    unsigned u = __float_as_uint(f);
    u += 0x7FFF + ((u >> 16) & 1);          // round-to-nearest-even
    return (u16)(u >> 16);
}
__device__ __forceinline__ float bf2f(u16 u){
    return __uint_as_float((unsigned)u << 16);
}

// Async global->LDS, 16 B per lane. LDS dest must be wave-uniform base + lane*16.
__device__ __forceinline__ void async_copy16(const void* g, void* l) {
    __builtin_amdgcn_global_load_lds(
        (const __attribute__((address_space(1))) unsigned int*)g,
        (__attribute__((address_space(3))) unsigned int*)l, 16, 0, 0);
}

// ---------------------------------------------------------------------------
// f32 -> bf16 elementwise convert (n % 4 == 0)
// ---------------------------------------------------------------------------
__global__ __launch_bounds__(256) void cvt_f32_bf16_kernel(
    const float* __restrict__ in, u16* __restrict__ out, int n)
{
    const int i = (blockIdx.x*256 + threadIdx.x)*4;
    if (i < n) {
        float4 v = *(const float4*)&in[i];
        u16x4 w = { f2bf(v.x), f2bf(v.y), f2bf(v.z), f2bf(v.w) };
        *(u16x4*)&out[i] = w;
    }
}

// ---------------------------------------------------------------------------
// Transpose + convert: in [R][C] f32  ->  out [C][R] bf16 (out pitch = R).
// ---------------------------------------------------------------------------
__global__ __launch_bounds__(256) void transpose_cvt_kernel(
    const float* __restrict__ in, u16* __restrict__ out, int R, int C)
{
    __shared__ u16 tile[64][65];
    const int r0 = blockIdx.y*64, c0 = blockIdx.x*64;
    const int tr = threadIdx.x >> 4;          // 0..15
    const int tc = (threadIdx.x & 15) * 4;    // 0,4,..60
    #pragma unroll
    for (int i = 0; i < 4; i++) {
        const int r = tr + i*16;
        float4 v = *(const float4*)&in[(size_t)(r0 + r)*C + c0 + tc];
        tile[tc+0][r] = f2bf(v.x);
        tile[tc+1][r] = f2bf(v.y);
        tile[tc+2][r] = f2bf(v.z);
        tile[tc+3][r] = f2bf(v.w);
    }
    __syncthreads();
    #pragma unroll
    for (int i = 0; i < 4; i++) {
        const int c = tr + i*16;
        u16x4 w = { tile[c][tc+0], tile[c][tc+1], tile[c][tc+2], tile[c][tc+3] };
        *(u16x4*)&out[(size_t)(c0 + c)*R + r0 + tc] = w;
    }
}

// ---------------------------------------------------------------------------
// bf16 transpose of the V segment of the merged qkv buffer:
//   in:  qkv[(b*T+t)*QKVP + VOFF + kvh*HD_ + d]
//   out: vt[((b*KV_+kvh)*HD_ + d)*T_ + t]
// ---------------------------------------------------------------------------
__global__ __launch_bounds__(256) void transpose_v_kernel(
    const u16* __restrict__ qkv, u16* __restrict__ vt)
{
    __shared__ u16 tile[64][65];
    const int t0 = blockIdx.x*64;
    const int d0 = blockIdx.y*64;              // 0 or 64
    const int bk = blockIdx.z;                 // b*KV_+kvh
    const int tr = threadIdx.x >> 4;           // 0..15
    const int tc = (threadIdx.x & 15) * 4;     // 0,4,..60
    #pragma unroll
    for (int i = 0; i < 4; i++) {
        const int t = t0 + tr + i*16;
        u16x4 v = *(const u16x4*)&qkv[(size_t)((bk>>2)*T_ + t)*QKVP + VOFF
                                      + (bk&3)*HD_ + d0 + tc];
        tile[tc+0][tr+i*16] = v[0];
        tile[tc+1][tr+i*16] = v[1];
        tile[tc+2][tr+i*16] = v[2];
        tile[tc+3][tr+i*16] = v[3];
    }
    __syncthreads();
    #pragma unroll
    for (int i = 0; i < 4; i++) {
        const int d = tr + i*16;
        u16x4 w = { tile[d][tc+0], tile[d][tc+1], tile[d][tc+2], tile[d][tc+3] };
        *(u16x4*)&vt[((size_t)bk*HD_ + d0 + d)*T_ + t0 + tc] = w;
    }
}

// ---------------------------------------------------------------------------
// m97-style MFMA GEMM with pitches: C[.,N] = A @ Bt^T, bf16 in, f32 acc.
// 128x128 tile, BK=32, 256 threads (4 waves, 2x2 quadrants of 64x64).
// ---------------------------------------------------------------------------
#define GBM 128
#define GBN 128
#define GBK 32

template<bool OUT_BF16>
__global__ __launch_bounds__(256) void gemm_mfma_kernel(
    const u16* __restrict__ A, const u16* __restrict__ Bt,
    void* __restrict__ C, int N, int K, int lda, int ldb, int ldc)
{
    __shared__ __align__(16) u16 As[GBM][GBK];
    __shared__ __align__(16) u16 Bs[GBN][GBK];
    const int tid  = threadIdx.x;
    const int lane = tid & 63;
    const int wave = tid >> 6;
    const int l15  = lane & 15;
    const int quad = lane >> 4;
    const int wr   = (wave >> 1) * 64;
    const int wc   = (wave & 1) * 64;
    const size_t row0 = (size_t)blockIdx.y * GBM;
    const size_t col0 = (size_t)blockIdx.x * GBN;

    f32x4 acc[4][4];
    #pragma unroll
    for (int i = 0; i < 4; i++)
        #pragma unroll
        for (int j = 0; j < 4; j++)
            acc[i][j] = (f32x4){0.f,0.f,0.f,0.f};

    for (int k0 = 0; k0 < K; k0 += GBK) {
        #pragma unroll
        for (int c = 0; c < 2; c++) {
            const int e = (c*256 + tid) * 8;
            const int r = e >> 5, cc = e & 31;
            async_copy16(A  + (row0 + r)*lda + k0 + cc, &As[r][cc]);
            async_copy16(Bt + (col0 + r)*ldb + k0 + cc, &Bs[r][cc]);
        }
        __syncthreads();

        short8 af[4], bf[4];
        #pragma unroll
        for (int i = 0; i < 4; i++)
            af[i] = *(const short8*)&As[wr + i*16 + l15][quad*8];
        #pragma unroll
        for (int j = 0; j < 4; j++)
            bf[j] = *(const short8*)&Bs[wc + j*16 + l15][quad*8];
        #pragma unroll
        for (int i = 0; i < 4; i++)
            #pragma unroll
            for (int j = 0; j < 4; j++)
                acc[i][j] = __builtin_amdgcn_mfma_f32_16x16x32_bf16(
                    af[i], bf[j], acc[i][j], 0, 0, 0);
        __syncthreads();
    }

    #pragma unroll
    for (int i = 0; i < 4; i++)
        #pragma unroll
        for (int r = 0; r < 4; r++) {
            const size_t row = row0 + wr + i*16 + quad*4 + r;
            #pragma unroll
            for (int j = 0; j < 4; j++) {
                const size_t col = col0 + wc + j*16 + l15;
                if (OUT_BF16) ((u16*)C)[row*ldc + col] = f2bf(acc[i][j][r]);
                else          ((float*)C)[row*ldc + col] = acc[i][j][r];
            }
        }
}

// ---------------------------------------------------------------------------
// Fused RMSNorm + RoPE, in place on bf16 rows inside the pitched qkv buffer.
// post_scale folds 1/sqrt(HD) into q rows (1.0 for k rows).
// ---------------------------------------------------------------------------
__global__ __launch_bounds__(128) void rmsnorm_rope_kernel(
    u16* __restrict__ qk, const float* __restrict__ scale,
    const float* __restrict__ cosT, const float* __restrict__ sinT,
    int heads_per_token, int head_off, float post_scale)
{
    const int row   = blockIdx.x;
    const int d     = threadIdx.x;
    const int token = row / heads_per_token;
    const int hidx  = row % heads_per_token;
    const int t     = token % T_;
    u16* p = qk + (size_t)token*QKVP + head_off + hidx*HD_;

    float v = bf2f(p[d]);
    __shared__ float red[HD_];
    __shared__ float xs[HD_];
    red[d] = v*v;
    __syncthreads();
    #pragma unroll
    for (int s = 64; s > 0; s >>= 1) {
        if (d < s) red[d] += red[d + s];
        __syncthreads();
    }
    const float rms = rsqrtf(red[0] * (1.0f/HD_) + EPS_);
    const float xn  = v * rms * scale[d];
    xs[d] = xn;
    __syncthreads();
    const float part = xs[d ^ 1];
    const float rot  = (d & 1) ? part : -part;
    p[d] = f2bf((xn*cosT[(size_t)t*HD_ + d] + rot*sinT[(size_t)t*HD_ + d]) * post_scale);
}

// ---------------------------------------------------------------------------
// Flash-style causal GQA attention v4.
//  - PAIRED q-tiles: block handles q-tile (31-p) then p -> every block does
//    exactly 33 k-tile rounds; 512 uniform blocks, zero tail.
//  - FIXED-MAX softmax: rmsnorm bounds |s| <= 11.32 (||q||~1 scaled,
//    ||k||=sqrt(128)) so exp cannot overflow; no max tracking, no alpha
//    rescale, no per-tile shfl chains. Row-sum deferred: per-lane partials,
//    one shfl reduce in the epilogue.
//  - Q A-frags in registers; LDS = K 16KB + V^T 16KB + P 8KB = 40KB.
// O written in-place into the q segment of qkv (disjoint from k/v segments).
// ---------------------------------------------------------------------------
#define BQ  64
#define BKV 64

__global__ __launch_bounds__(256, 4) void attn_mfma5_kernel(
    const u16* __restrict__ qkv, const u16* __restrict__ Vtg)
{
    __shared__ __align__(16) u16 Ks[16][BKV][8];   // [k-chunk][key][8]    16 KB
    __shared__ __align__(16) u16 Vt[8][HD_][8];    // [key-chunk][d][8]    16 KB
    __shared__ __align__(16) u16 Pb[4][8][16][8];  // [wave][key-chunk][row][8] 8 KB

    const int pr   = blockIdx.x;                   // pair index 0..15
    const int h    = blockIdx.y;
    const int b    = blockIdx.z;
    const int kvh  = h >> 2;                       // H_/KV_ = 4
    const int tid  = threadIdx.x;
    const int lane = tid & 63;
    const int wave = tid >> 6;
    const int l15  = lane & 15;
    const int quad = lane >> 4;
    const int NT   = T_ / BQ;                      // 32

    for (int phase = 0; phase < 2; phase++) {
        const int qt = phase ? pr : (NT - 1 - pr); // heavy tile first
        const int q0 = qt * BQ;

        // ---- Q A-fragments straight to registers (row = wave*16+l15) ----
        short8 qf[4];
        {
            const u16* qbase = qkv + (size_t)(b*T_ + q0 + wave*16 + l15)*QKVP + h*HD_;
            #pragma unroll
            for (int kt = 0; kt < 4; kt++)
                qf[kt] = *(const short8*)(qbase + (kt*4 + quad)*8);
        }

        float lsum[4] = {0.f, 0.f, 0.f, 0.f};      // per-lane partial row sums
        f32x4 oacc[8];
        #pragma unroll
        for (int cv = 0; cv < 8; cv++) oacc[cv] = (f32x4){0.f,0.f,0.f,0.f};

        const int ntiles = qt + 1;
        for (int t = 0; t < ntiles; t++) {
            const int k0 = t * BKV;
            __syncthreads();        // all waves done reading prev K/V (or prev phase)

            // ---- stage K tile [16cc][64key] from k segment ----
            #pragma unroll
            for (int it = 0; it < 4; it++) {
                const int n   = it*256 + tid;
                const int cc  = n >> 6;
                const int key = n & 63;
                async_copy16(qkv + (size_t)(b*T_ + k0 + key)*QKVP + KOFF + kvh*HD_ + cc*8,
                             &Ks[cc][key][0]);
            }
            // ---- stage V^T tile [8cc][128d] ----
            #pragma unroll
            for (int it = 0; it < 4; it++) {
                const int n  = it*256 + tid;
                const int cc = n >> 7;
                const int d  = n & 127;
                async_copy16(Vtg + ((size_t)(b*KV_ + kvh)*HD_ + d)*T_ + k0 + cc*8,
                             &Vt[cc][d][0]);
            }
            __syncthreads();        // drains vmcnt(0): staged data visible

            // ---- S = Q @ K^T : wave slab (16 rows) x 64 keys ----
            f32x4 s[4];
            #pragma unroll
            for (int c = 0; c < 4; c++) s[c] = (f32x4){0.f,0.f,0.f,0.f};
            #pragma unroll
            for (int kt = 0; kt < 4; kt++) {
                #pragma unroll
                for (int c = 0; c < 4; c++) {
                    short8 bf = *(const short8*)&Ks[kt*4 + quad][c*16 + l15][0];
                    s[c] = __builtin_amdgcn_mfma_f32_16x16x32_bf16(qf[kt], bf, s[c], 0, 0, 0);
                }
            }

            // ---- fixed-max softmax: mask (diag only), exp, partial sums ----
            if (t == ntiles - 1) {
                const int qrow0 = q0 + wave*16 + quad*4;
                #pragma unroll
                for (int r = 0; r < 4; r++)
                    #pragma unroll
                    for (int c = 0; c < 4; c++) {
                        const int key = k0 + c*16 + l15;
                        if (key > qrow0 + r) s[c][r] = -1e30f;
                    }
            }
            #pragma unroll
            for (int r = 0; r < 4; r++)
                #pragma unroll
                for (int c = 0; c < 4; c++) {
                    const float p = __expf(s[c][r]);
                    s[c][r] = p;
                    lsum[r] += p;
                }

            // ---- P -> wave-private LDS (A-operand layout), no barrier needed ----
            #pragma unroll
            for (int r = 0; r < 4; r++)
                #pragma unroll
                for (int c = 0; c < 4; c++)
                    Pb[wave][c*2 + (l15 >> 3)][quad*4 + r][l15 & 7] = f2bf(s[c][r]);

            // ---- O += P @ V (no rescale: fixed-max) ----
            #pragma unroll
            for (int kt2 = 0; kt2 < 2; kt2++) {
                short8 a = *(const short8*)&Pb[wave][kt2*4 + quad][l15][0];
                #pragma unroll
                for (int cv = 0; cv < 8; cv++) {
                    short8 vf = *(const short8*)&Vt[kt2*4 + quad][cv*16 + l15][0];
                    oacc[cv] = __builtin_amdgcn_mfma_f32_16x16x32_bf16(a, vf, oacc[cv], 0, 0, 0);
                }
            }
        }

        // ---- epilogue: reduce row sums once, divide, write O in place ----
        #pragma unroll
        for (int r = 0; r < 4; r++) {
            float tot = lsum[r];
            #pragma unroll
            for (int off = 1; off < 16; off <<= 1)
                tot += __shfl_xor(tot, off, 16);
            const float linv = 1.0f / tot;
            u16* orow = (u16*)qkv + (size_t)(b*T_ + q0 + wave*16 + quad*4 + r)*QKVP
                        + h*HD_ + l15;
            #pragma unroll
            for (int cv = 0; cv < 8; cv++)
                orow[cv*16] = f2bf(oacc[cv][r] * linv);
        }
    }
}

// ---------------------------------------------------------------------------
extern "C" void kernel_launch(void* const* d_in, const int* in_sizes, int n_in,
                              void* d_out, int out_size, void* d_ws, size_t ws_size,
                              hipStream_t stream)
{
    const float* x    = (const float*)d_in[0];   // [B,T,D]
    const float* Wq   = (const float*)d_in[1];   // [D, H*HD]
    const float* Wk   = (const float*)d_in[2];   // [D, KV*HD]
    const float* Wv   = (const float*)d_in[3];   // [D, KV*HD]
    const float* Wo   = (const float*)d_in[4];   // [H*HD, D]
    const float* qsc  = (const float*)d_in[5];   // [HD]
    const float* ksc  = (const float*)d_in[6];   // [HD]
    const float* cosT = (const float*)d_in[7];   // [T, HD]
    const float* sinT = (const float*)d_in[8];   // [T, HD]
    float* out = (float*)d_out;

    // Workspace carve (bf16, ~67 MB total)
    u16* xb     = (u16*)d_ws;                      // [BT, 2048]
    u16* Wqkvt  = xb    + (size_t)BT_*D_;          // [3072, 2048]
    u16* Wot    = Wqkvt + (size_t)QKVP*D_;         // [2048, 2048]
    u16* qkv    = Wot   + (size_t)D_*(H_*HD_);     // [BT, 3072]
    u16* vtg    = qkv   + (size_t)BT_*QKVP;        // [B*KV, HD, T]

    // ---- convert x; transpose+convert weights (concatenated qkv weight) ----
    cvt_f32_bf16_kernel<<<(BT_*D_)/1024, 256, 0, stream>>>(x, xb, BT_*D_);
    transpose_cvt_kernel<<<dim3((H_*HD_)/64,  D_/64), 256, 0, stream>>>(
        Wq, Wqkvt, D_, H_*HD_);
    transpose_cvt_kernel<<<dim3((KV_*HD_)/64, D_/64), 256, 0, stream>>>(
        Wk, Wqkvt + (size_t)KOFF*D_, D_, KV_*HD_);
    transpose_cvt_kernel<<<dim3((KV_*HD_)/64, D_/64), 256, 0, stream>>>(
        Wv, Wqkvt + (size_t)VOFF*D_, D_, KV_*HD_);
    transpose_cvt_kernel<<<dim3(D_/64, (H_*HD_)/64),  256, 0, stream>>>(
        Wo, Wot, H_*HD_, D_);

    // ---- merged q|k|v projection: [4096,2048] x [2048,3072] ----
    gemm_mfma_kernel<true><<<dim3(QKVP/GBN, BT_/GBM), 256, 0, stream>>>(
        xb, Wqkvt, qkv, QKVP, D_, D_, D_, QKVP);

    // ---- RMSNorm + RoPE in place (q gets 1/sqrt(HD) folded in) ----
    rmsnorm_rope_kernel<<<BT_*H_,  HD_, 0, stream>>>(
        qkv, qsc, cosT, sinT, H_, 0, 0.08838834764831845f);
    rmsnorm_rope_kernel<<<BT_*KV_, HD_, 0, stream>>>(
        qkv, ksc, cosT, sinT, KV_, KOFF, 1.0f);

    // ---- V^T into global [b*KV][d][t] ----
    transpose_v_kernel<<<dim3(T_/64, HD_/64, B_*KV_), 256, 0, stream>>>(qkv, vtg);

    // ---- Flash attention v4: paired q-tiles, 512 uniform blocks ----
    attn_mfma5_kernel<<<dim3(T_/BQ/2, H_, B_), 256, 0, stream>>>(qkv, vtg);

    // ---- out = attn @ Wo (f32 out): A = q segment, pitch 3072 ----
    gemm_mfma_kernel<false><<<dim3(D_/GBN, BT_/GBM), 256, 0, stream>>>(
        qkv, Wot, out, D_, D_, QKVP, D_, D_);
}